// Round 5
// baseline (940.306 us; speedup 1.0000x reference)
//
#include <hip/hip_runtime.h>
#include <cstddef>

#define THRESH 1e-6f
#define SPIN_LIMIT (1 << 20)

__device__ __forceinline__ float thrf(float x) { return x > THRESH ? x : 0.0f; }
__device__ __forceinline__ float sigm(float x) { return 1.0f / (1.0f + expf(-x)); }
__device__ __forceinline__ void fma4(float4& c, float a, float4 b) {
    c.x += a * b.x; c.y += a * b.y; c.z += a * b.z; c.w += a * b.w;
}
__device__ __forceinline__ void macc4(float4& a, float4 w, float4 h) {
    a.x += w.x * h.x; a.y += w.y * h.y; a.z += w.z * h.z; a.w += w.w * h.w;
}
__device__ __forceinline__ float hsum4(float4 a) { return a.x + a.y + a.z + a.w; }

// ---------------------------------------------------------------------------
// K1: fused gather+MLP GEMM (unchanged — proven).
// ---------------------------------------------------------------------------
__global__ __launch_bounds__(256) void k_embed_gemm(const int* __restrict__ tok,
                                                    const float* __restrict__ W1,
                                                    const float* __restrict__ b1,
                                                    const float* __restrict__ W2,
                                                    const float* __restrict__ b2,
                                                    float* __restrict__ emb) {
    constexpr int BM = 64, BN = 64, BK = 32, K = 512, N = 256;
    __shared__ float As[BK][BM + 1];
    __shared__ float Bs[BK][BN];

    const int tid = threadIdx.x;
    const int bm = blockIdx.x * BM;
    const int bn = blockIdx.y * BN;
    const int tn = (tid & 15) * 4;
    const int tm = (tid >> 4) * 4;

    float acc[4][4] = {};

    for (int k0 = 0; k0 < K; k0 += BK) {
        for (int i = tid; i < BM * BK / 4; i += 256) {
            int c4 = (i & (BK / 4 - 1)) * 4;
            int r  = i / (BK / 4);
            int tv = tok[bm + r];
            float4 v  = *(const float4*)(W1 + (size_t)tv * K + k0 + c4);
            float4 bb = *(const float4*)(b1 + k0 + c4);
            As[c4 + 0][r] = thrf(v.x + bb.x);
            As[c4 + 1][r] = thrf(v.y + bb.y);
            As[c4 + 2][r] = thrf(v.z + bb.z);
            As[c4 + 3][r] = thrf(v.w + bb.w);
        }
        for (int i = tid; i < BK * BN / 4; i += 256) {
            int n4 = (i & 15) * 4;
            int kk = i >> 4;
            *(float4*)&Bs[kk][n4] = *(const float4*)(W2 + (size_t)(k0 + kk) * N + bn + n4);
        }
        __syncthreads();

        for (int k = 0; k < BK; ++k) {
            float a0 = As[k][tm + 0], a1 = As[k][tm + 1];
            float a2 = As[k][tm + 2], a3 = As[k][tm + 3];
            float b0 = Bs[k][tn + 0], b1v = Bs[k][tn + 1];
            float b2v = Bs[k][tn + 2], b3v = Bs[k][tn + 3];
            acc[0][0] += a0 * b0;  acc[0][1] += a0 * b1v;
            acc[0][2] += a0 * b2v; acc[0][3] += a0 * b3v;
            acc[1][0] += a1 * b0;  acc[1][1] += a1 * b1v;
            acc[1][2] += a1 * b2v; acc[1][3] += a1 * b3v;
            acc[2][0] += a2 * b0;  acc[2][1] += a2 * b1v;
            acc[2][2] += a2 * b2v; acc[2][3] += a2 * b3v;
            acc[3][0] += a3 * b0;  acc[3][1] += a3 * b1v;
            acc[3][2] += a3 * b2v; acc[3][3] += a3 * b3v;
        }
        __syncthreads();
    }

    const float4 bv = *(const float4*)(b2 + bn + tn);
    for (int i = 0; i < 4; ++i) {
        int m = bm + tm + i;
        float4 o;
        o.x = thrf(acc[i][0] + bv.x);
        o.y = thrf(acc[i][1] + bv.y);
        o.z = thrf(acc[i][2] + bv.z);
        o.w = thrf(acc[i][3] + bv.w);
        *(float4*)(emb + (size_t)m * N + bn + tn) = o;
    }
}

// ---------------------------------------------------------------------------
// K2: x_proj = emb @ W_ih^T + b_ih  (unchanged — proven).
// ---------------------------------------------------------------------------
__global__ __launch_bounds__(256) void k_xproj(const float* __restrict__ emb,   // (4096,256)
                                               const float* __restrict__ W_ih,  // (1536,256)
                                               const float* __restrict__ b_ih,  // (1536)
                                               float* __restrict__ xp) {        // (4096,1536)
    constexpr int BM = 128, BJ = 64, BK = 32, K = 256, J = 1536;
    __shared__ __align__(16) float As[BK][BM + 4];
    __shared__ __align__(16) float Bs[BK][BJ + 4];
    const int tid = threadIdx.x;
    const int bm = blockIdx.x * BM;
    const int bj = blockIdx.y * BJ;
    const int tj = (tid & 15) * 4;
    const int tm = (tid >> 4) * 8;

    float4 acc[8];
#pragma unroll
    for (int i = 0; i < 8; ++i) acc[i] = make_float4(0.f, 0.f, 0.f, 0.f);

    for (int k0 = 0; k0 < K; k0 += BK) {
#pragma unroll
        for (int p = 0; p < 4; ++p) {
            int i = tid + p * 256;
            int c4 = (i & 7) * 4, r = i >> 3;
            float4 v = *(const float4*)(emb + (size_t)(bm + r) * K + k0 + c4);
            As[c4 + 0][r] = v.x; As[c4 + 1][r] = v.y;
            As[c4 + 2][r] = v.z; As[c4 + 3][r] = v.w;
        }
#pragma unroll
        for (int p = 0; p < 2; ++p) {
            int i = tid + p * 256;
            int c4 = (i & 7) * 4, r = i >> 3;
            float4 v = *(const float4*)(W_ih + (size_t)(bj + r) * K + k0 + c4);
            Bs[c4 + 0][r] = v.x; Bs[c4 + 1][r] = v.y;
            Bs[c4 + 2][r] = v.z; Bs[c4 + 3][r] = v.w;
        }
        __syncthreads();

#pragma unroll 8
        for (int k = 0; k < BK; ++k) {
            float4 b4 = *(const float4*)&Bs[k][tj];
            float4 a0 = *(const float4*)&As[k][tm];
            float4 a1 = *(const float4*)&As[k][tm + 4];
            fma4(acc[0], a0.x, b4); fma4(acc[1], a0.y, b4);
            fma4(acc[2], a0.z, b4); fma4(acc[3], a0.w, b4);
            fma4(acc[4], a1.x, b4); fma4(acc[5], a1.y, b4);
            fma4(acc[6], a1.z, b4); fma4(acc[7], a1.w, b4);
        }
        __syncthreads();
    }

    const float4 bb = *(const float4*)(b_ih + bj + tj);
#pragma unroll
    for (int i = 0; i < 8; ++i) {
        float4 o = make_float4(acc[i].x + bb.x, acc[i].y + bb.y,
                               acc[i].z + bb.z, acc[i].w + bb.w);
        *(float4*)(xp + (size_t)(bm + tm + i) * J + bj + tj) = o;
    }
}

// ---------------------------------------------------------------------------
// K3: GRU scan — register-resident weights + LL exchange, in-wave reduce.
// 128 blocks x 512 threads = 8 groups (bid&7) x 16 members (bid>>3).
// Member owns j-slice [m*32, m*32+32); group owns batches [g*4, g*4+4).
// Thread layout (lane = tid&63, wave = tid>>6):
//   kc   = lane&15  -> contiguous k-chunk [32*kc, 32*kc+32)
//   jlow = lane>>4  -> j = m*32 + wave*4 + jlow
// All 16 kc of a j live in ONE wave -> the k-reduce is 4 shfl_xor; no red[]
// LDS stage, no extra barrier, no bank conflicts.  Lanes kc<4 finalize batch
// kc for their j and publish IMMEDIATELY after the shuffles (per-wave publish
// -> producer path no longer waits for the whole block).
// LL safety (per-wave publish): tag t+1 publish requires passing sync(t),
// which requires all producers' tag-t, which requires every member passed
// sync(t-1), i.e. fully consumed tag t-1 -> overwritten parity slot is dead.
// h LDS is double-buffered (parity) -> exactly ONE __syncthreads per step.
// Skewed LDS layout (chunk kc at offset 36*kc) -> dot reads are 2-way bank
// aliased (free).  Each staging thread's 4 LL words come from ONE producer
// wave (k-run of 4 inside one chunk) -> minimal straggler gating.
// ---------------------------------------------------------------------------
__global__ __launch_bounds__(512) void k_scan(const float* __restrict__ xp,    // (4096,1536)
                                              const float* __restrict__ W_hh,  // (1536,512)
                                              const float* __restrict__ b_hh,  // (1536)
                                              unsigned long long* __restrict__ hx, // (2,32,512) u64
                                              float* __restrict__ h_out) {     // (32,512)
    constexpr int CH = 576;                        // 512 + 16*4 skew pad
    __shared__ __align__(16) float hl[2][4 * CH];  // 2 x 9216 B
    const int tid  = threadIdx.x;
    const int g    = blockIdx.x & 7;
    const int m    = blockIdx.x >> 3;
    const int lane = tid & 63;
    const int wave = tid >> 6;                     // 0..7
    const int kc   = lane & 15;
    const int jlow = lane >> 4;                    // 0..3
    const int jglob = m * 32 + wave * 4 + jlow;
    const int hoff  = kc * 36;                     // skewed chunk base

    // ---- W rows -> registers (constant across all 128 steps) ----
    float4 wr[8], wz[8], wn[8];
#pragma unroll
    for (int i = 0; i < 8; ++i) {
        const int k = kc * 32 + i * 4;
        wr[i] = *(const float4*)(W_hh + (size_t)jglob * 512 + k);
        wz[i] = *(const float4*)(W_hh + (size_t)(512 + jglob) * 512 + k);
        wn[i] = *(const float4*)(W_hh + (size_t)(1024 + jglob) * 512 + k);
    }

    // finalizer lanes (kc<4): handle (j = jglob, batch = g*4+kc)
    const int bg = g * 4 + kc;
    float bhr = 0.f, bhz = 0.f, bhn = 0.f, hprev = 0.f;
    if (kc < 4) {
        bhr = b_hh[jglob];
        bhz = b_hh[512 + jglob];
        bhn = b_hh[1024 + jglob];
    }

    // h(0) = 0 (buffer 0); ordered before t=0 dot by the in-loop sync
    for (int i = tid; i < 4 * CH; i += 512) hl[0][i] = 0.f;

    // staging assignment: 4 consecutive LL words (one producer wave each)
    const int sflat = tid * 4;
    const int sb = sflat >> 9, sk = sflat & 511;
    const int sdst = sb * CH + sk + ((sk >> 5) << 2);

    for (int t = 0; t < 128; ++t) {
        // x(t) issued first — latency hides under the LL poll
        float xr = 0.f, xz = 0.f, xn = 0.f;
        if (kc < 4) {
            const float* xrow = xp + (size_t)(t * 32 + bg) * 1536;
            xr = xrow[jglob];
            xz = xrow[512 + jglob];
            xn = xrow[1024 + jglob];
        }

        if (t > 0) {
            const unsigned tag = (unsigned)t;
            unsigned long long* base = hx + (size_t)(t & 1) * 16384
                                          + (size_t)(g * 4) * 512 + sflat;
            unsigned long long v0 = __hip_atomic_load(base + 0, __ATOMIC_RELAXED, __HIP_MEMORY_SCOPE_AGENT);
            unsigned long long v1 = __hip_atomic_load(base + 1, __ATOMIC_RELAXED, __HIP_MEMORY_SCOPE_AGENT);
            unsigned long long v2 = __hip_atomic_load(base + 2, __ATOMIC_RELAXED, __HIP_MEMORY_SCOPE_AGENT);
            unsigned long long v3 = __hip_atomic_load(base + 3, __ATOMIC_RELAXED, __HIP_MEMORY_SCOPE_AGENT);
            int spins = 0;
            while (((unsigned)(v0 >> 32) != tag) | ((unsigned)(v1 >> 32) != tag) |
                   ((unsigned)(v2 >> 32) != tag) | ((unsigned)(v3 >> 32) != tag)) {
                if ((unsigned)(v0 >> 32) != tag)
                    v0 = __hip_atomic_load(base + 0, __ATOMIC_RELAXED, __HIP_MEMORY_SCOPE_AGENT);
                if ((unsigned)(v1 >> 32) != tag)
                    v1 = __hip_atomic_load(base + 1, __ATOMIC_RELAXED, __HIP_MEMORY_SCOPE_AGENT);
                if ((unsigned)(v2 >> 32) != tag)
                    v2 = __hip_atomic_load(base + 2, __ATOMIC_RELAXED, __HIP_MEMORY_SCOPE_AGENT);
                if ((unsigned)(v3 >> 32) != tag)
                    v3 = __hip_atomic_load(base + 3, __ATOMIC_RELAXED, __HIP_MEMORY_SCOPE_AGENT);
                if (++spins > SPIN_LIMIT) break;
                __builtin_amdgcn_s_sleep(1);
            }
            union { unsigned u; float f; } c0, c1, c2, c3;
            c0.u = (unsigned)v0; c1.u = (unsigned)v1;
            c2.u = (unsigned)v2; c3.u = (unsigned)v3;
            *(float4*)&hl[t & 1][sdst] = make_float4(c0.f, c1.f, c2.f, c3.f);
        }
        __syncthreads();   // the single per-step barrier

        // ---- dot: 3 gates x 4 batches over k in [32kc, 32kc+32) ----
        const float* hb = hl[t & 1];
        float p[3][4];
#pragma unroll
        for (int b = 0; b < 4; ++b) {
            float4 ar = make_float4(0.f, 0.f, 0.f, 0.f), az = ar, an = ar;
            const float* h0 = hb + b * CH + hoff;
#pragma unroll
            for (int i = 0; i < 8; ++i) {
                float4 h4 = *(const float4*)(h0 + i * 4);
                macc4(ar, wr[i], h4);
                macc4(az, wz[i], h4);
                macc4(an, wn[i], h4);
            }
            p[0][b] = hsum4(ar); p[1][b] = hsum4(az); p[2][b] = hsum4(an);
        }

        // ---- in-wave reduce over kc (lane bits 0..3) ----
#pragma unroll
        for (int gg = 0; gg < 3; ++gg)
#pragma unroll
            for (int b = 0; b < 4; ++b) {
                float v = p[gg][b];
                v += __shfl_xor(v, 1);
                v += __shfl_xor(v, 2);
                v += __shfl_xor(v, 4);
                v += __shfl_xor(v, 8);
                p[gg][b] = v;
            }

        // ---- finalize + per-wave publish: lane kc handles batch kc ----
        if (kc < 4) {
            float sr, sz, sn;
            if      (kc == 0) { sr = p[0][0]; sz = p[1][0]; sn = p[2][0]; }
            else if (kc == 1) { sr = p[0][1]; sz = p[1][1]; sn = p[2][1]; }
            else if (kc == 2) { sr = p[0][2]; sz = p[1][2]; sn = p[2][2]; }
            else              { sr = p[0][3]; sz = p[1][3]; sn = p[2][3]; }
            float r  = sigm(xr + sr + bhr);
            float z  = sigm(xz + sz + bhz);
            float n  = tanhf(xn + r * (sn + bhn));
            float hn = (1.0f - z) * n + z * hprev;
            hprev = hn;
            if (t < 127) {
                union { float f; unsigned u; } cv; cv.f = hn;
                __hip_atomic_store(hx + (size_t)((t + 1) & 1) * 16384
                                      + (size_t)bg * 512 + jglob,
                                   ((unsigned long long)(unsigned)(t + 1) << 32) | cv.u,
                                   __ATOMIC_RELAXED, __HIP_MEMORY_SCOPE_AGENT);
            } else {
                h_out[(size_t)bg * 512 + jglob] = hn;
            }
        }
        // no bottom barrier: next stage writes the OTHER hl buffer
    }
}

// ---------------------------------------------------------------------------
// K4: head (unchanged).
// ---------------------------------------------------------------------------
__global__ __launch_bounds__(256) void k_head(const float* __restrict__ h,
                                              const float* __restrict__ W3,
                                              const float* __restrict__ b3,
                                              float* __restrict__ out) {
    const int b = blockIdx.x;
    const int o = threadIdx.x;
    const float* hrow = h + (size_t)b * 512;
    float acc = b3[o];
#pragma unroll 8
    for (int k = 0; k < 512; ++k)
        acc += hrow[k] * W3[(size_t)k * 256 + o];
    out[(size_t)b * 256 + o] = acc;
}

// ---------------------------------------------------------------------------
extern "C" void kernel_launch(void* const* d_in, const int* in_sizes, int n_in,
                              void* d_out, int out_size, void* d_ws, size_t ws_size,
                              hipStream_t stream) {
    // 0:input 1:W1 2:b1 3:W2 4:b2 5:W_ih 6:W_hh 7:b_ih 8:b_hh 9:W3 10:b3
    const int*   tok  = (const int*)d_in[0];
    const float* W1   = (const float*)d_in[1];
    const float* b1   = (const float*)d_in[2];
    const float* W2   = (const float*)d_in[3];
    const float* b2   = (const float*)d_in[4];
    const float* W_ih = (const float*)d_in[5];
    const float* W_hh = (const float*)d_in[6];
    const float* b_ih = (const float*)d_in[7];
    const float* b_hh = (const float*)d_in[8];
    const float* W3   = (const float*)d_in[9];
    const float* b3   = (const float*)d_in[10];
    float* out = (float*)d_out;
    (void)ws_size;

    // workspace (floats):
    //   emb : 1,048,576      (4096x256)
    //   xp  : 6,291,456      (4096x1536)
    //   hx  : 65,536 f-equiv (2x32x512 u64 LL slots; exact-tag poll makes
    //                         0xAA poison harmless — no memset needed)
    //   hfin: 16,384         (32x512)
    float* ws   = (float*)d_ws;
    float* emb  = ws;
    float* xp   = ws + 1048576;
    unsigned long long* hx = (unsigned long long*)(ws + 7340032);  // 8B-aligned
    float* hfin = ws + 7340032 + 65536;

    {   // fused embedding MLP
        dim3 grd(4096 / 64, 256 / 64);
        k_embed_gemm<<<grd, 256, 0, stream>>>(tok, W1, b1, W2, b2, emb);
    }
    {   // input projections for all timesteps (b_ih folded in)
        dim3 grd(4096 / 128, 1536 / 64);
        k_xproj<<<grd, 256, 0, stream>>>(emb, W_ih, b_ih, xp);
    }
    // LL-exchange GRU scan: 8 groups x 16 members, in-wave reduce
    k_scan<<<128, 512, 0, stream>>>(xp, W_hh, b_hh, hx, hfin);

    // head on final hidden state
    k_head<<<32, 256, 0, stream>>>(hfin, W3, b3, out);
}

// Round 6
// 873.730 us; speedup vs baseline: 1.0762x; 1.0762x over previous
//
#include <hip/hip_runtime.h>
#include <cstddef>

#define THRESH 1e-6f
#define SPIN_LIMIT (1 << 20)

__device__ __forceinline__ float thrf(float x) { return x > THRESH ? x : 0.0f; }
__device__ __forceinline__ float sigm(float x) { return 1.0f / (1.0f + expf(-x)); }
__device__ __forceinline__ void fma4(float4& c, float a, float4 b) {
    c.x += a * b.x; c.y += a * b.y; c.z += a * b.z; c.w += a * b.w;
}
__device__ __forceinline__ void macc4(float4& a, float4 w, float4 h) {
    a.x += w.x * h.x; a.y += w.y * h.y; a.z += w.z * h.z; a.w += w.w * h.w;
}
__device__ __forceinline__ float hsum4(float4 a) { return a.x + a.y + a.z + a.w; }

// ---------------------------------------------------------------------------
// K1: fused gather+MLP GEMM (unchanged — proven).
// ---------------------------------------------------------------------------
__global__ __launch_bounds__(256) void k_embed_gemm(const int* __restrict__ tok,
                                                    const float* __restrict__ W1,
                                                    const float* __restrict__ b1,
                                                    const float* __restrict__ W2,
                                                    const float* __restrict__ b2,
                                                    float* __restrict__ emb) {
    constexpr int BM = 64, BN = 64, BK = 32, K = 512, N = 256;
    __shared__ float As[BK][BM + 1];
    __shared__ float Bs[BK][BN];

    const int tid = threadIdx.x;
    const int bm = blockIdx.x * BM;
    const int bn = blockIdx.y * BN;
    const int tn = (tid & 15) * 4;
    const int tm = (tid >> 4) * 4;

    float acc[4][4] = {};

    for (int k0 = 0; k0 < K; k0 += BK) {
        for (int i = tid; i < BM * BK / 4; i += 256) {
            int c4 = (i & (BK / 4 - 1)) * 4;
            int r  = i / (BK / 4);
            int tv = tok[bm + r];
            float4 v  = *(const float4*)(W1 + (size_t)tv * K + k0 + c4);
            float4 bb = *(const float4*)(b1 + k0 + c4);
            As[c4 + 0][r] = thrf(v.x + bb.x);
            As[c4 + 1][r] = thrf(v.y + bb.y);
            As[c4 + 2][r] = thrf(v.z + bb.z);
            As[c4 + 3][r] = thrf(v.w + bb.w);
        }
        for (int i = tid; i < BK * BN / 4; i += 256) {
            int n4 = (i & 15) * 4;
            int kk = i >> 4;
            *(float4*)&Bs[kk][n4] = *(const float4*)(W2 + (size_t)(k0 + kk) * N + bn + n4);
        }
        __syncthreads();

        for (int k = 0; k < BK; ++k) {
            float a0 = As[k][tm + 0], a1 = As[k][tm + 1];
            float a2 = As[k][tm + 2], a3 = As[k][tm + 3];
            float b0 = Bs[k][tn + 0], b1v = Bs[k][tn + 1];
            float b2v = Bs[k][tn + 2], b3v = Bs[k][tn + 3];
            acc[0][0] += a0 * b0;  acc[0][1] += a0 * b1v;
            acc[0][2] += a0 * b2v; acc[0][3] += a0 * b3v;
            acc[1][0] += a1 * b0;  acc[1][1] += a1 * b1v;
            acc[1][2] += a1 * b2v; acc[1][3] += a1 * b3v;
            acc[2][0] += a2 * b0;  acc[2][1] += a2 * b1v;
            acc[2][2] += a2 * b2v; acc[2][3] += a2 * b3v;
            acc[3][0] += a3 * b0;  acc[3][1] += a3 * b1v;
            acc[3][2] += a3 * b2v; acc[3][3] += a3 * b3v;
        }
        __syncthreads();
    }

    const float4 bv = *(const float4*)(b2 + bn + tn);
    for (int i = 0; i < 4; ++i) {
        int m = bm + tm + i;
        float4 o;
        o.x = thrf(acc[i][0] + bv.x);
        o.y = thrf(acc[i][1] + bv.y);
        o.z = thrf(acc[i][2] + bv.z);
        o.w = thrf(acc[i][3] + bv.w);
        *(float4*)(emb + (size_t)m * N + bn + tn) = o;
    }
}

// ---------------------------------------------------------------------------
// K2: x_proj = emb @ W_ih^T + b_ih  (unchanged — proven).
// ---------------------------------------------------------------------------
__global__ __launch_bounds__(256) void k_xproj(const float* __restrict__ emb,   // (4096,256)
                                               const float* __restrict__ W_ih,  // (1536,256)
                                               const float* __restrict__ b_ih,  // (1536)
                                               float* __restrict__ xp) {        // (4096,1536)
    constexpr int BM = 128, BJ = 64, BK = 32, K = 256, J = 1536;
    __shared__ __align__(16) float As[BK][BM + 4];
    __shared__ __align__(16) float Bs[BK][BJ + 4];
    const int tid = threadIdx.x;
    const int bm = blockIdx.x * BM;
    const int bj = blockIdx.y * BJ;
    const int tj = (tid & 15) * 4;
    const int tm = (tid >> 4) * 8;

    float4 acc[8];
#pragma unroll
    for (int i = 0; i < 8; ++i) acc[i] = make_float4(0.f, 0.f, 0.f, 0.f);

    for (int k0 = 0; k0 < K; k0 += BK) {
#pragma unroll
        for (int p = 0; p < 4; ++p) {
            int i = tid + p * 256;
            int c4 = (i & 7) * 4, r = i >> 3;
            float4 v = *(const float4*)(emb + (size_t)(bm + r) * K + k0 + c4);
            As[c4 + 0][r] = v.x; As[c4 + 1][r] = v.y;
            As[c4 + 2][r] = v.z; As[c4 + 3][r] = v.w;
        }
#pragma unroll
        for (int p = 0; p < 2; ++p) {
            int i = tid + p * 256;
            int c4 = (i & 7) * 4, r = i >> 3;
            float4 v = *(const float4*)(W_ih + (size_t)(bj + r) * K + k0 + c4);
            Bs[c4 + 0][r] = v.x; Bs[c4 + 1][r] = v.y;
            Bs[c4 + 2][r] = v.z; Bs[c4 + 3][r] = v.w;
        }
        __syncthreads();

#pragma unroll 8
        for (int k = 0; k < BK; ++k) {
            float4 b4 = *(const float4*)&Bs[k][tj];
            float4 a0 = *(const float4*)&As[k][tm];
            float4 a1 = *(const float4*)&As[k][tm + 4];
            fma4(acc[0], a0.x, b4); fma4(acc[1], a0.y, b4);
            fma4(acc[2], a0.z, b4); fma4(acc[3], a0.w, b4);
            fma4(acc[4], a1.x, b4); fma4(acc[5], a1.y, b4);
            fma4(acc[6], a1.z, b4); fma4(acc[7], a1.w, b4);
        }
        __syncthreads();
    }

    const float4 bb = *(const float4*)(b_ih + bj + tj);
#pragma unroll
    for (int i = 0; i < 8; ++i) {
        float4 o = make_float4(acc[i].x + bb.x, acc[i].y + bb.y,
                               acc[i].z + bb.z, acc[i].w + bb.w);
        *(float4*)(xp + (size_t)(bm + tm + i) * J + bj + tj) = o;
    }
}

// ---------------------------------------------------------------------------
// K3: GRU scan — R4's proven 256-thread shape + in-wave reduce.
// 256 blocks x 256 threads = 8 groups (bid&7) x 32 members (bid>>3).
// Member owns j-slice [m*16, m*16+16); group owns batches [g*4, g*4+4).
// Thread layout (lane = tid&63, wave = tid>>6, 4 waves/block):
//   kc   = lane&15  -> contiguous k-chunk [32*kc, 32*kc+32)
//   jlow = lane>>4  -> j = m*16 + wave*4 + jlow
// All 16 kc of a j live in ONE wave -> k-reduce = 4 shfl_xor; no red[] LDS,
// no second barrier, no bank conflicts.  Lanes kc<4 finalize batch kc for
// their j and publish IMMEDIATELY after their wave's shuffles.
// __launch_bounds__(256, 1): explicitly allow max VGPRs.  R5's regression
// was the compiler dropping to 100 VGPRs at 512 thr (weights rematerialized
// from memory every step: FETCH +8.4MB, VALUBusy halved).  R3/R4 held 228
// VGPRs at 256 thr — this kernel must show VGPR ~200+ or the graft failed.
// LL safety (per-wave publish): publishing tag t+1 requires passing the
// step-t barrier, which requires all producers' tag-t, which requires every
// member passed barrier t-1, i.e. fully consumed tag t-1 -> the parity slot
// being overwritten is dead.  ONE __syncthreads per step.
// ---------------------------------------------------------------------------
__global__ __launch_bounds__(256, 1) void k_scan(const float* __restrict__ xp,    // (4096,1536)
                                                 const float* __restrict__ W_hh,  // (1536,512)
                                                 const float* __restrict__ b_hh,  // (1536)
                                                 unsigned long long* __restrict__ hx, // (2,32,512) u64
                                                 float* __restrict__ h_out) {     // (32,512)
    constexpr int CH = 576;                        // 512 + 16*4 skew pad
    __shared__ __align__(16) float hl[2][4 * CH];  // 2 x 9216 B
    const int tid  = threadIdx.x;
    const int g    = blockIdx.x & 7;
    const int m    = blockIdx.x >> 3;              // 0..31
    const int lane = tid & 63;
    const int wave = tid >> 6;                     // 0..3
    const int kc   = lane & 15;
    const int jlow = lane >> 4;                    // 0..3
    const int jglob = m * 16 + wave * 4 + jlow;
    const int hoff  = kc * 36;                     // skewed chunk base

    // ---- W rows -> registers (constant across all 128 steps) ----
    float4 wr[8], wz[8], wn[8];
#pragma unroll
    for (int i = 0; i < 8; ++i) {
        const int k = kc * 32 + i * 4;
        wr[i] = *(const float4*)(W_hh + (size_t)jglob * 512 + k);
        wz[i] = *(const float4*)(W_hh + (size_t)(512 + jglob) * 512 + k);
        wn[i] = *(const float4*)(W_hh + (size_t)(1024 + jglob) * 512 + k);
    }

    // finalizer lanes (kc<4): handle (j = jglob, batch = g*4+kc)
    const int bg = g * 4 + kc;
    float bhr = 0.f, bhz = 0.f, bhn = 0.f, hprev = 0.f;
    if (kc < 4) {
        bhr = b_hh[jglob];
        bhz = b_hh[512 + jglob];
        bhn = b_hh[1024 + jglob];
    }

    // h(0) = 0 (buffer 0); ordered before the t=0 dot by the in-loop barrier
    for (int i = tid; i < 4 * CH; i += 256) hl[0][i] = 0.f;

    // staging assignment: 8 consecutive LL words (j-run of 8 inside one
    // batch; spans exactly 2 producer waves of one member)
    const int sflat = tid * 8;
    const int sb = sflat >> 9, sk = sflat & 511;
    const int sdst = sb * CH + sk + ((sk >> 5) << 2);

    for (int t = 0; t < 128; ++t) {
        // x(t) issued first — latency hides under the LL poll
        float xr = 0.f, xz = 0.f, xn = 0.f;
        if (kc < 4) {
            const float* xrow = xp + (size_t)(t * 32 + bg) * 1536;
            xr = xrow[jglob];
            xz = xrow[512 + jglob];
            xn = xrow[1024 + jglob];
        }

        if (t > 0) {
            const unsigned tag = (unsigned)t;
            unsigned long long* base = hx + (size_t)(t & 1) * 16384
                                          + (size_t)(g * 4) * 512 + sflat;
            unsigned long long v[8];
#pragma unroll
            for (int p = 0; p < 8; ++p)
                v[p] = __hip_atomic_load(base + p, __ATOMIC_RELAXED, __HIP_MEMORY_SCOPE_AGENT);
            int spins = 0;
            for (;;) {
                bool all = true;
#pragma unroll
                for (int p = 0; p < 8; ++p) {
                    if ((unsigned)(v[p] >> 32) != tag) {
                        all = false;
                        v[p] = __hip_atomic_load(base + p, __ATOMIC_RELAXED, __HIP_MEMORY_SCOPE_AGENT);
                    }
                }
                if (all || ++spins > SPIN_LIMIT) break;
                __builtin_amdgcn_s_sleep(1);
            }
            union { unsigned u; float f; } c0, c1, c2, c3, c4, c5, c6, c7;
            c0.u = (unsigned)v[0]; c1.u = (unsigned)v[1];
            c2.u = (unsigned)v[2]; c3.u = (unsigned)v[3];
            c4.u = (unsigned)v[4]; c5.u = (unsigned)v[5];
            c6.u = (unsigned)v[6]; c7.u = (unsigned)v[7];
            *(float4*)&hl[t & 1][sdst]     = make_float4(c0.f, c1.f, c2.f, c3.f);
            *(float4*)&hl[t & 1][sdst + 4] = make_float4(c4.f, c5.f, c6.f, c7.f);
        }
        __syncthreads();   // the single per-step barrier

        // ---- dot: 3 gates x 4 batches over k in [32kc, 32kc+32) ----
        const float* hb = hl[t & 1];
        float p[3][4];
#pragma unroll
        for (int b = 0; b < 4; ++b) {
            float4 ar = make_float4(0.f, 0.f, 0.f, 0.f), az = ar, an = ar;
            const float* h0 = hb + b * CH + hoff;
#pragma unroll
            for (int i = 0; i < 8; ++i) {
                float4 h4 = *(const float4*)(h0 + i * 4);
                macc4(ar, wr[i], h4);
                macc4(az, wz[i], h4);
                macc4(an, wn[i], h4);
            }
            p[0][b] = hsum4(ar); p[1][b] = hsum4(az); p[2][b] = hsum4(an);
        }

        // ---- in-wave reduce over kc (lane bits 0..3) ----
#pragma unroll
        for (int gg = 0; gg < 3; ++gg)
#pragma unroll
            for (int b = 0; b < 4; ++b) {
                float v = p[gg][b];
                v += __shfl_xor(v, 1);
                v += __shfl_xor(v, 2);
                v += __shfl_xor(v, 4);
                v += __shfl_xor(v, 8);
                p[gg][b] = v;
            }

        // ---- finalize + per-wave publish: lane kc handles batch kc ----
        if (kc < 4) {
            float sr, sz, sn;
            if      (kc == 0) { sr = p[0][0]; sz = p[1][0]; sn = p[2][0]; }
            else if (kc == 1) { sr = p[0][1]; sz = p[1][1]; sn = p[2][1]; }
            else if (kc == 2) { sr = p[0][2]; sz = p[1][2]; sn = p[2][2]; }
            else              { sr = p[0][3]; sz = p[1][3]; sn = p[2][3]; }
            float r  = sigm(xr + sr + bhr);
            float z  = sigm(xz + sz + bhz);
            float n  = tanhf(xn + r * (sn + bhn));
            float hn = (1.0f - z) * n + z * hprev;
            hprev = hn;
            if (t < 127) {
                union { float f; unsigned u; } cv; cv.f = hn;
                __hip_atomic_store(hx + (size_t)((t + 1) & 1) * 16384
                                      + (size_t)bg * 512 + jglob,
                                   ((unsigned long long)(unsigned)(t + 1) << 32) | cv.u,
                                   __ATOMIC_RELAXED, __HIP_MEMORY_SCOPE_AGENT);
            } else {
                h_out[(size_t)bg * 512 + jglob] = hn;
            }
        }
        // no bottom barrier: next staging writes the OTHER hl buffer
    }
}

// ---------------------------------------------------------------------------
// K4: head (unchanged).
// ---------------------------------------------------------------------------
__global__ __launch_bounds__(256) void k_head(const float* __restrict__ h,
                                              const float* __restrict__ W3,
                                              const float* __restrict__ b3,
                                              float* __restrict__ out) {
    const int b = blockIdx.x;
    const int o = threadIdx.x;
    const float* hrow = h + (size_t)b * 512;
    float acc = b3[o];
#pragma unroll 8
    for (int k = 0; k < 512; ++k)
        acc += hrow[k] * W3[(size_t)k * 256 + o];
    out[(size_t)b * 256 + o] = acc;
}

// ---------------------------------------------------------------------------
extern "C" void kernel_launch(void* const* d_in, const int* in_sizes, int n_in,
                              void* d_out, int out_size, void* d_ws, size_t ws_size,
                              hipStream_t stream) {
    // 0:input 1:W1 2:b1 3:W2 4:b2 5:W_ih 6:W_hh 7:b_ih 8:b_hh 9:W3 10:b3
    const int*   tok  = (const int*)d_in[0];
    const float* W1   = (const float*)d_in[1];
    const float* b1   = (const float*)d_in[2];
    const float* W2   = (const float*)d_in[3];
    const float* b2   = (const float*)d_in[4];
    const float* W_ih = (const float*)d_in[5];
    const float* W_hh = (const float*)d_in[6];
    const float* b_ih = (const float*)d_in[7];
    const float* b_hh = (const float*)d_in[8];
    const float* W3   = (const float*)d_in[9];
    const float* b3   = (const float*)d_in[10];
    float* out = (float*)d_out;
    (void)ws_size;

    // workspace (floats):
    //   emb : 1,048,576      (4096x256)
    //   xp  : 6,291,456      (4096x1536)
    //   hx  : 65,536 f-equiv (2x32x512 u64 LL slots; exact-tag poll makes
    //                         0xAA poison harmless — no memset needed)
    //   hfin: 16,384         (32x512)
    float* ws   = (float*)d_ws;
    float* emb  = ws;
    float* xp   = ws + 1048576;
    unsigned long long* hx = (unsigned long long*)(ws + 7340032);  // 8B-aligned
    float* hfin = ws + 7340032 + 65536;

    {   // fused embedding MLP
        dim3 grd(4096 / 64, 256 / 64);
        k_embed_gemm<<<grd, 256, 0, stream>>>(tok, W1, b1, W2, b2, emb);
    }
    {   // input projections for all timesteps (b_ih folded in)
        dim3 grd(4096 / 128, 1536 / 64);
        k_xproj<<<grd, 256, 0, stream>>>(emb, W_ih, b_ih, xp);
    }
    // LL-exchange GRU scan: 8 groups x 32 members, in-wave reduce
    k_scan<<<256, 256, 0, stream>>>(xp, W_hh, b_hh, hx, hfin);

    // head on final hidden state
    k_head<<<32, 256, 0, stream>>>(hfin, W3, b3, out);
}